// Round 15
// baseline (283.526 us; speedup 1.0000x reference)
//
#include <hip/hip_runtime.h>
#include <math.h>

#define HID 32
#define HOR 12
#define NB  256   // first-level blocks; k_binscan's 256 threads own one block each
#define GSH 8     // group shift: 256 nodes per group (ng=196 <= 256)
#define GW  256   // group width
#define NPT 4     // nodes per thread in k_gates
#define TILE 2048 // edges per staged-scatter tile (both keyings staged at once)
#define SBINS 256 // padded bin count for the staged scatter (ng <= 256)

__device__ __forceinline__ float sigmoidf_(float x) { return 1.0f / (1.0f + expf(-x)); }

// ---------------------------------------------------------------------------
// Round-14 champion (241.1 us) with two glue reductions:
//  - k_scatter: ONE pass over the edges staging BOTH keyings per tile
//    (was two passes re-reading src/w; -12.8MB reads, half the tile barriers).
//  - k_binbase folded into k_binscan via the last-block pattern
//    (writers: store -> threadfence -> atomicAdd; last block re-reads binTot
//    with agent-scope atomic loads and does both base scans). One less launch.
// Everything else byte-identical to round 14.
// ---------------------------------------------------------------------------

// per-block histograms of src>>8 and dst>>8, written bin-major.
// Also computes flag: bit0 = any h0 nonzero, bit1 = any c0 nonzero.
__global__ __launch_bounds__(1024) void k_hist(const int* __restrict__ src,
                                               const int* __restrict__ dst,
                                               int* __restrict__ hist,
                                               const float* __restrict__ h0,
                                               const float* __restrict__ c0,
                                               int* __restrict__ flag,
                                               int E, int chunk, int ng, int total4) {
    __shared__ int hS[GW], hD[GW];
    int t = threadIdx.x, b = blockIdx.x;
    for (int i = t; i < ng; i += 1024) { hS[i] = 0; hD[i] = 0; }
    __syncthreads();
    int beg = b * chunk, end = min(E, beg + chunk);
    for (int e = beg + t; e < end; e += 1024) {
        atomicAdd(&hS[src[e] >> GSH], 1);
        atomicAdd(&hD[dst[e] >> GSH], 1);
    }
    // flag scan: grid-stride float4 over h0 and c0 (N*32 divisible by 4)
    bool ah = false, ac = false;
    for (int i = b * 1024 + t; i < total4; i += NB * 1024) {
        float4 a = ((const float4*)h0)[i];
        float4 c = ((const float4*)c0)[i];
        ah |= (a.x != 0.0f) | (a.y != 0.0f) | (a.z != 0.0f) | (a.w != 0.0f);
        ac |= (c.x != 0.0f) | (c.y != 0.0f) | (c.z != 0.0f) | (c.w != 0.0f);
    }
    unsigned long long bh = __ballot(ah);
    unsigned long long bc = __ballot(ac);
    if ((t & 63) == 0) {
        int m = (bh ? 1 : 0) | (bc ? 2 : 0);
        if (m) atomicOr(flag, m);
    }
    __syncthreads();
    for (int i = t; i < ng; i += 1024) {
        hist[(size_t)i * NB + b] = hS[i];               // S bins: [0, ng)
        hist[((size_t)ng + i) * NB + b] = hD[i];        // D bins: [ng, 2ng)
    }
}

// per-bin exclusive scan across the NB blocks; LAST block also computes the
// cross-bin bases (former k_binbase) via the decoupled last-block pattern.
__global__ __launch_bounds__(256) void k_binscan(const int* __restrict__ hist,
                                                 int* __restrict__ off,
                                                 int* __restrict__ binTot,
                                                 int* __restrict__ baseS, int* __restrict__ baseD,
                                                 int* __restrict__ rowptr,
                                                 int* __restrict__ counter,
                                                 int ng2, int ng, int E, int N) {
    __shared__ int s[256];
    int b2 = blockIdx.x, t = threadIdx.x;
    int v = hist[(size_t)b2 * NB + t];                  // coalesced
    s[t] = v;
    __syncthreads();
    for (int o = 1; o < 256; o <<= 1) {
        int x = (t >= o) ? s[t - o] : 0;
        __syncthreads();
        s[t] += x;
        __syncthreads();
    }
    off[(size_t)t * ng2 + b2] = s[t] - v;               // block-major (scattered)
    if (t == 255) binTot[b2] = s[255];

    // last block performs the base scans
    __threadfence();
    __shared__ int lastFlag;
    if (t == 0) lastFlag = (atomicAdd(counter, 1) == ng2 - 1) ? 1 : 0;
    __syncthreads();
    if (!lastFlag) return;

    __shared__ int bufS[256], bufD[256];
    int vS = 0, vD = 0;
    if (t < ng) {
        vS = __hip_atomic_load(&binTot[t], __ATOMIC_RELAXED, __HIP_MEMORY_SCOPE_AGENT);
        vD = __hip_atomic_load(&binTot[ng + t], __ATOMIC_RELAXED, __HIP_MEMORY_SCOPE_AGENT);
    }
    bufS[t] = vS; bufD[t] = vD;
    __syncthreads();
    for (int o = 1; o < 256; o <<= 1) {
        int xS = (t >= o) ? bufS[t - o] : 0;
        int xD = (t >= o) ? bufD[t - o] : 0;
        __syncthreads();
        bufS[t] += xS; bufD[t] += xD;
        __syncthreads();
    }
    if (t < ng) { baseS[t] = bufS[t] - vS; baseD[t] = bufD[t] - vD; }
    if (t == 0) { baseS[ng] = E; baseD[ng] = E; rowptr[N] = E; }
}

// single-pass tile-staged scatter: both keyings staged per 2048-edge tile.
// Per tile: rank (LDS atomics) -> dual 256-bin scan -> sort into LDS ->
// coalesced flush of both staging buffers.
__global__ __launch_bounds__(1024) void k_scatter(const int* __restrict__ src,
                                                  const int* __restrict__ dst,
                                                  const float* __restrict__ w,
                                                  const int* __restrict__ off,
                                                  const int* __restrict__ baseS,
                                                  const int* __restrict__ baseD,
                                                  int2* __restrict__ tmpS, int2* __restrict__ tmpD,
                                                  int E, int chunk, int ng) {
    __shared__ int2 stageS[TILE], stageD[TILE];   // 16 KB each
    __shared__ int cntS[SBINS], cntD[SBINS];      // tile-local offsets
    __shared__ int gcS[SBINS], gcD[SBINS];        // running global cursors
    int t = threadIdx.x, b = blockIdx.x;
    int beg = b * chunk, end = min(E, beg + chunk);
    int ng2 = 2 * ng;
    if (t < ng) {
        gcS[t] = off[(size_t)b * ng2 + t] + baseS[t];
        gcD[t] = off[(size_t)b * ng2 + ng + t] + baseD[t];
    }
    __syncthreads();

    for (int tb = beg; tb < end; tb += TILE) {
        int tcount = min(TILE, end - tb);
        if (t < SBINS) { cntS[t] = 0; cntD[t] = 0; }
        __syncthreads();

        // load + rank both keyings (2 items per thread)
        int gS_[2], rS_[2], gD_[2], rD_[2];
        int2 pS_[2], pD_[2];
        #pragma unroll
        for (int u = 0; u < 2; ++u) {
            int li = u * 1024 + t;
            gS_[u] = -1;
            if (li < tcount) {
                int e = tb + li;
                int s = src[e], d = dst[e];
                int wb = __float_as_int(w[e]);
                int gs = s >> GSH, gd = d >> GSH;
                pS_[u] = make_int2(s, wb);
                pD_[u] = make_int2(s | ((d & (GW - 1)) << 16) | (gd << 24), wb);
                gS_[u] = gs; gD_[u] = gd;
                rS_[u] = atomicAdd(&cntS[gs], 1);
                rD_[u] = atomicAdd(&cntD[gd], 1);
            }
        }
        __syncthreads();

        // dual exclusive scan: threads 0-255 scan cntS, 256-511 scan cntD
        int lt = t & 255;
        bool isS = (t < 256), isD2 = (t >= 256 && t < 512);
        int origS = isS ? cntS[lt] : 0;
        int origD = isD2 ? cntD[lt] : 0;
        for (int o = 1; o < SBINS; o <<= 1) {
            int vS = (isS && lt >= o) ? cntS[lt - o] : 0;
            int vD = (isD2 && lt >= o) ? cntD[lt - o] : 0;
            __syncthreads();
            if (isS && lt >= o) cntS[lt] += vS;
            if (isD2 && lt >= o) cntD[lt] += vD;
            __syncthreads();
        }
        if (isS) cntS[lt] -= origS;                 // exclusive
        if (isD2) cntD[lt] -= origD;
        __syncthreads();

        // place into staging (tiles now sorted by group)
        #pragma unroll
        for (int u = 0; u < 2; ++u) {
            if (gS_[u] >= 0) {
                stageS[cntS[gS_[u]] + rS_[u]] = pS_[u];
                stageD[cntD[gD_[u]] + rD_[u]] = pD_[u];
            }
        }
        __syncthreads();

        // coalesced flush: consecutive i in a group -> consecutive addrs
        for (int i = t; i < tcount; i += 1024) {
            int2 p = stageS[i];
            int g = p.x >> GSH;                      // s>>8 (< 256)
            tmpS[gcS[g] + (i - cntS[g])] = p;
            int2 q = stageD[i];
            int g2 = (q.x >> 24) & 255;
            tmpD[gcD[g2] + (i - cntD[g2])] = q;
        }
        __syncthreads();

        if (isS) gcS[lt] += origS;
        if (isD2) gcD[lt] += origD;
        __syncthreads();
    }
}

// per src-group: LDS float histogram over low 8 bits -> dinv (no global atomics)
__global__ __launch_bounds__(1024) void k_degsum(const int2* __restrict__ tmpS,
                                                 const int* __restrict__ baseS,
                                                 float* __restrict__ dinv, int N) {
    __shared__ float h[GW];
    int g = blockIdx.x, t = threadIdx.x;
    if (t < GW) h[t] = 0.0f;
    __syncthreads();
    int beg = baseS[g], end = baseS[g + 1];
    for (int i = beg + t; i < end; i += 1024) {
        int2 p = tmpS[i];
        atomicAdd(&h[p.x & (GW - 1)], __int_as_float(p.y));
    }
    __syncthreads();
    if (t < GW) {
        int n = (g << GSH) + t;
        if (n < N) { float s = h[t]; dinv[n] = (s > 0.0f) ? rsqrtf(s) : 0.0f; }
    }
}

// per dst-group: low-bits count + scan -> rowptr; then bin edges to exact dst,
// computing nw now that dinv exists. Within-dst order is arbitrary (sum).
__global__ __launch_bounds__(1024) void k_scatter2(const int2* __restrict__ tmpD,
                                                   const int* __restrict__ baseD,
                                                   const float* __restrict__ dinv,
                                                   int* __restrict__ rowptr,
                                                   int2* __restrict__ epair, int N) {
    __shared__ int h[GW], cur[GW];
    int g = blockIdx.x, t = threadIdx.x;
    if (t < GW) h[t] = 0;
    __syncthreads();
    int beg = baseD[g], end = baseD[g + 1];
    for (int i = beg + t; i < end; i += 1024) atomicAdd(&h[(tmpD[i].x >> 16) & (GW - 1)], 1);
    __syncthreads();
    int v = (t < GW) ? h[t] : 0;
    for (int o = 1; o < GW; o <<= 1) {
        int x = (t < GW && t >= o) ? h[t - o] : 0;
        __syncthreads();
        if (t < GW && t >= o) h[t] += x;
        __syncthreads();
    }
    if (t < GW) {
        int excl = h[t] - v;
        int n = (g << GSH) + t;
        if (n < N) rowptr[n] = beg + excl;
        cur[t] = beg + excl;
    }
    __syncthreads();
    for (int i = beg + t; i < end; i += 1024) {
        int2 p = tmpD[i];
        int low = (p.x >> 16) & (GW - 1);
        int s = p.x & 0xFFFF;
        int pos = atomicAdd(&cur[low], 1);
        float nw = -dinv[s] * __int_as_float(p.y) * dinv[(g << GSH) + low];
        epair[pos] = make_int2(s, __float_as_int(nw));
    }
}

// per dst node (32 lanes = 32 feats): accumulate LX (and LH if h0 nonzero)
__global__ __launch_bounds__(256) void k_gather(const int* __restrict__ rowptr,
                                                const int2* __restrict__ epair,
                                                const float* __restrict__ X,
                                                const float* __restrict__ H0,
                                                const int* __restrict__ hflag,
                                                float* __restrict__ LX, float* __restrict__ LH,
                                                int N) {
    int tid = blockIdx.x * 256 + threadIdx.x;
    int n = tid >> 5;
    int f = tid & 31;
    if (n >= N) return;
    int beg = rowptr[n], end = rowptr[n + 1];
    float acc = 0.0f, accH = 0.0f;
    int fl = *hflag;
    if (fl & 1) {
        #pragma unroll 4
        for (int i = beg; i < end; ++i) {
            int2 p = epair[i];
            float w = __int_as_float(p.y);
            acc  += w * X[(p.x << 5) + f];
            accH += w * H0[(p.x << 5) + f];
        }
    } else {
        #pragma unroll 4
        for (int i = beg; i < end; ++i) {
            int2 p = epair[i];
            acc += __int_as_float(p.y) * X[(p.x << 5) + f];
        }
    }
    LX[(n << 5) + f] = acc;
    if (fl & 1) LH[(n << 5) + f] = accH;   // LH is logically 0 otherwise; never read then
}

// Per (node-group g of NPT nodes, out-feature j): fused LSTM cell (no head).
// Fast path (h0==0 && c0==0, detected at runtime): F-gate dead (C = I*T),
// h/lh terms are exact zero-adds -> 3 gates x 2 input types. Bit-identical.
__global__ __launch_bounds__(256) void k_gates(
    const float* __restrict__ X, const float* __restrict__ LX,
    const float* __restrict__ H0, const float* __restrict__ LH,
    const float* __restrict__ C0,
    const float* __restrict__ Wx, const float* __restrict__ bx,
    const float* __restrict__ Wh, const float* __restrict__ bh,
    const float* __restrict__ wc, const float* __restrict__ b,
    const int* __restrict__ flag,
    float* __restrict__ outH, float* __restrict__ outC, int N) {
    int tid = blockIdx.x * 256 + threadIdx.x;
    int g = tid >> 5;           // node group
    int j = tid & 31;           // output feature
    int n0 = g * NPT;
    if (n0 >= N) return;
    int cnt = min(NPT, N - n0);
    int f2 = *flag;

    if (f2 == 0) {
        // ---- fast path: h0 == 0 and c0 == 0 ----
        float xk[NPT], lxk[NPT];
        #pragma unroll
        for (int i = 0; i < NPT; ++i) { xk[i] = 0.0f; lxk[i] = 0.0f; }
        for (int i = 0; i < cnt; ++i) {
            int base = (n0 + i) << 5;
            xk[i]  = X[base + j];
            lxk[i] = LX[base + j];
        }
        float p0[NPT], p2[NPT], p3[NPT];
        float b0 = bx[0 * HID + j] + bh[0 * HID + j] + b[0 * HID + j];
        float b2 = bx[2 * HID + j] + bh[2 * HID + j] + b[2 * HID + j];
        float b3 = bx[3 * HID + j] + bh[3 * HID + j] + b[3 * HID + j];
        #pragma unroll
        for (int i = 0; i < NPT; ++i) { p0[i] = b0; p2[i] = b2; p3[i] = b3; }

        #pragma unroll 4
        for (int k = 0; k < HID; ++k) {
            int row = k * HID + j;
            float w00 = Wx[row],            w01 = Wx[1024 + row];
            float w20 = Wx[2 * 2048 + row], w21 = Wx[2 * 2048 + 1024 + row];
            float w30 = Wx[3 * 2048 + row], w31 = Wx[3 * 2048 + 1024 + row];
            #pragma unroll
            for (int i = 0; i < NPT; ++i) {
                float xv  = __shfl(xk[i],  k, 32);
                float lxv = __shfl(lxk[i], k, 32);
                p0[i] += xv * w00 + lxv * w01;
                p2[i] += xv * w20 + lxv * w21;
                p3[i] += xv * w30 + lxv * w31;
            }
        }

        float wc2 = wc[2 * HID + j];
        for (int i = 0; i < cnt; ++i) {
            int base = (n0 + i) << 5;
            float I = sigmoidf_(p0[i]);
            float T = tanhf(p2[i]);
            float C = I * T;
            float O = sigmoidf_(p3[i] + wc2 * C);
            outH[base + j] = O * tanhf(C);
            outC[base + j] = C;
        }
        return;
    }

    // ---- general path ----
    float xk[NPT], lxk[NPT], hk[NPT], lhk[NPT];
    #pragma unroll
    for (int i = 0; i < NPT; ++i) { xk[i] = 0.0f; lxk[i] = 0.0f; hk[i] = 0.0f; lhk[i] = 0.0f; }
    for (int i = 0; i < cnt; ++i) {
        int base = (n0 + i) << 5;
        xk[i]  = X[base + j];
        lxk[i] = LX[base + j];
        hk[i]  = H0[base + j];
        lhk[i] = (f2 & 1) ? LH[base + j] : 0.0f;   // LH only valid if h0 nonzero
    }

    float pre[4][NPT];
    #pragma unroll
    for (int gt = 0; gt < 4; ++gt) {
        float bb = bx[gt * HID + j] + bh[gt * HID + j] + b[gt * HID + j];
        #pragma unroll
        for (int i = 0; i < NPT; ++i) pre[gt][i] = bb;
    }

    #pragma unroll 2
    for (int k = 0; k < HID; ++k) {
        float w0[4], w1[4], w2[4], w3[4];
        int row = k * HID + j;
        #pragma unroll
        for (int gt = 0; gt < 4; ++gt) {
            w0[gt] = Wx[gt * 2048 + row];
            w1[gt] = Wx[gt * 2048 + 1024 + row];
            w2[gt] = Wh[gt * 2048 + row];
            w3[gt] = Wh[gt * 2048 + 1024 + row];
        }
        #pragma unroll
        for (int i = 0; i < NPT; ++i) {
            float xv  = __shfl(xk[i],  k, 32);
            float lxv = __shfl(lxk[i], k, 32);
            float hv  = __shfl(hk[i],  k, 32);
            float lhv = __shfl(lhk[i], k, 32);
            #pragma unroll
            for (int gt = 0; gt < 4; ++gt)
                pre[gt][i] += xv * w0[gt] + lxv * w1[gt] + hv * w2[gt] + lhv * w3[gt];
        }
    }

    float wc0 = wc[0 * HID + j], wc1 = wc[1 * HID + j], wc2 = wc[2 * HID + j];
    for (int i = 0; i < cnt; ++i) {
        int base = (n0 + i) << 5;
        float c0v = C0[base + j];
        float I  = sigmoidf_(pre[0][i] + wc0 * c0v);
        float Fg = sigmoidf_(pre[1][i] + wc1 * c0v);
        float T  = tanhf(pre[2][i]);
        float C  = Fg * c0v + I * T;
        float O  = sigmoidf_(pre[3][i] + wc2 * C);
        float H  = O * tanhf(C);
        outH[base + j] = H;
        outC[base + j] = C;
    }
}

// h[n,t] = b_lin[t] + sum_k relu(H[n,k]) * W_lin[k,t]
__global__ void k_head(const float* __restrict__ H, const float* __restrict__ Wl,
                       const float* __restrict__ bl, float* __restrict__ hout, int N) {
    int tid = blockIdx.x * 256 + threadIdx.x;
    int n = tid / HOR;
    int t = tid - n * HOR;
    if (n >= N) return;
    float acc = bl[t];
    #pragma unroll
    for (int k = 0; k < HID; ++k) {
        float v = H[(n << 5) + k];
        acc += fmaxf(v, 0.0f) * Wl[k * HOR + t];
    }
    hout[n * HOR + t] = acc;
}

extern "C" void kernel_launch(void* const* d_in, const int* in_sizes, int n_in,
                              void* d_out, int out_size, void* d_ws, size_t ws_size,
                              hipStream_t stream) {
    const float* x  = (const float*)d_in[0];
    const int*   ei = (const int*)d_in[1];
    const float* ew = (const float*)d_in[2];
    const float* Wx = (const float*)d_in[3];
    const float* bx = (const float*)d_in[4];
    const float* Wh = (const float*)d_in[5];
    const float* bh = (const float*)d_in[6];
    const float* wc = (const float*)d_in[7];
    const float* b  = (const float*)d_in[8];
    const float* Wl = (const float*)d_in[9];
    const float* bl = (const float*)d_in[10];
    const float* h0 = (const float*)d_in[11];
    const float* c0 = (const float*)d_in[12];

    int N = in_sizes[0] / HID;      // x is (N,1,32)
    int E = in_sizes[2];            // edge_weight is (E,)
    const int* src = ei;
    const int* dst = ei + E;

    int ng = (N + GW - 1) >> GSH;   // 196 groups (requires N <= 65536)
    int ng2 = 2 * ng;
    int chunk = (E + NB - 1) / NB;  // edges per hist/scatter block

    // workspace (4-byte units):
    // [tmpD 2E] [tmpS 2E (aliased by epair)] [LX N*32] [LH N*32] [rowptr N+1]
    // [hist ng2*NB] [off ng2*NB] [binTot 2048] [baseS ng+1] [baseD ng+1]
    // [dinv N] [flag 1] [counter 1]
    // tmpS is dead after k_degsum, so k_scatter2 may overwrite it with epair.
    int* wsi = (int*)d_ws;
    int2*  tmpD   = (int2*)wsi;
    int2*  tmpS   = (int2*)(wsi + 2 * (size_t)E);
    int2*  epair  = tmpS;                                // alias (see above)
    float* LX     = (float*)(wsi + 4 * (size_t)E);
    float* LH     = LX + (size_t)N * HID;
    int*   rowptr = (int*)(LH + (size_t)N * HID);
    int*   hist   = rowptr + (N + 1);
    int*   off    = hist + (size_t)ng2 * NB;
    int*   binTot = off + (size_t)ng2 * NB;
    int*   baseS  = binTot + 2048;
    int*   baseD  = baseS + (ng + 1);
    float* dinv   = (float*)(baseD + (ng + 1));
    int*   flag   = (int*)(dinv + N);
    int*   counter= flag + 1;

    float* hOut = (float*)d_out;            // (N,12)
    float* HOut = hOut + (size_t)N * HOR;   // (N,32)
    float* COut = HOut + (size_t)N * HID;   // (N,32)

    hipMemsetAsync(flag, 0, 2 * sizeof(int), stream);   // flag + counter

    k_hist<<<NB, 1024, 0, stream>>>(src, dst, hist, h0, c0, flag, E, chunk, ng, (N * HID) >> 2);
    k_binscan<<<ng2, 256, 0, stream>>>(hist, off, binTot, baseS, baseD, rowptr, counter,
                                       ng2, ng, E, N);
    k_scatter<<<NB, 1024, 0, stream>>>(src, dst, ew, off, baseS, baseD, tmpS, tmpD, E, chunk, ng);
    k_degsum<<<ng, 1024, 0, stream>>>(tmpS, baseS, dinv, N);
    k_scatter2<<<ng, 1024, 0, stream>>>(tmpD, baseD, dinv, rowptr, epair, N);

    k_gather<<<(N * HID + 255) / 256, 256, 0, stream>>>(rowptr, epair, x, h0, flag, LX, LH, N);

    int gThreads = ((N + NPT - 1) / NPT) * 32;
    k_gates<<<(gThreads + 255) / 256, 256, 0, stream>>>(x, LX, h0, LH, c0,
                                                        Wx, bx, Wh, bh, wc, b, flag,
                                                        HOut, COut, N);

    k_head<<<(N * HOR + 255) / 256, 256, 0, stream>>>(HOut, Wl, bl, hOut, N);
}

// Round 16
// 243.269 us; speedup vs baseline: 1.1655x; 1.1655x over previous
//
#include <hip/hip_runtime.h>
#include <math.h>

#define HID 32
#define HOR 12
#define NB  256   // first-level blocks; k_binscan's 256 threads own one block each
#define GSH 8     // group shift: 256 nodes per group (ng=196 <= 256)
#define GW  256   // group width
#define NPT 4     // nodes per thread in k_gates
#define TILE 2048 // edges per staged-scatter tile (both keyings staged at once)
#define SBINS 256 // padded bin count for the staged scatter (ng <= 256)

__device__ __forceinline__ float sigmoidf_(float x) { return 1.0f / (1.0f + expf(-x)); }

// ---------------------------------------------------------------------------
// Recovery: round-14 champion (241.1 us) structure. The r15 last-block
// binscan fusion is REVERTED (392 blocks x __threadfence() cost 42 us —
// device-scope fences in wide grids are far more expensive than the one
// launch they save). The r15 single-pass scatter is KEPT (neutral timing,
// -12.8MB reads). Everything else identical to round 14.
// ---------------------------------------------------------------------------

// per-block histograms of src>>8 and dst>>8, written bin-major.
// Also computes flag: bit0 = any h0 nonzero, bit1 = any c0 nonzero.
__global__ __launch_bounds__(1024) void k_hist(const int* __restrict__ src,
                                               const int* __restrict__ dst,
                                               int* __restrict__ hist,
                                               const float* __restrict__ h0,
                                               const float* __restrict__ c0,
                                               int* __restrict__ flag,
                                               int E, int chunk, int ng, int total4) {
    __shared__ int hS[GW], hD[GW];
    int t = threadIdx.x, b = blockIdx.x;
    for (int i = t; i < ng; i += 1024) { hS[i] = 0; hD[i] = 0; }
    __syncthreads();
    int beg = b * chunk, end = min(E, beg + chunk);
    for (int e = beg + t; e < end; e += 1024) {
        atomicAdd(&hS[src[e] >> GSH], 1);
        atomicAdd(&hD[dst[e] >> GSH], 1);
    }
    // flag scan: grid-stride float4 over h0 and c0 (N*32 divisible by 4)
    bool ah = false, ac = false;
    for (int i = b * 1024 + t; i < total4; i += NB * 1024) {
        float4 a = ((const float4*)h0)[i];
        float4 c = ((const float4*)c0)[i];
        ah |= (a.x != 0.0f) | (a.y != 0.0f) | (a.z != 0.0f) | (a.w != 0.0f);
        ac |= (c.x != 0.0f) | (c.y != 0.0f) | (c.z != 0.0f) | (c.w != 0.0f);
    }
    unsigned long long bh = __ballot(ah);
    unsigned long long bc = __ballot(ac);
    if ((t & 63) == 0) {
        int m = (bh ? 1 : 0) | (bc ? 2 : 0);
        if (m) atomicOr(flag, m);
    }
    __syncthreads();
    for (int i = t; i < ng; i += 1024) {
        hist[(size_t)i * NB + b] = hS[i];               // S bins: [0, ng)
        hist[((size_t)ng + i) * NB + b] = hD[i];        // D bins: [ng, 2ng)
    }
}

// per-bin exclusive scan across the NB blocks (one block per bin)
__global__ __launch_bounds__(256) void k_binscan(const int* __restrict__ hist,
                                                 int* __restrict__ off,
                                                 int* __restrict__ binTot, int ng2) {
    __shared__ int s[256];
    int b2 = blockIdx.x, t = threadIdx.x;
    int v = hist[(size_t)b2 * NB + t];                  // coalesced
    s[t] = v;
    __syncthreads();
    for (int o = 1; o < 256; o <<= 1) {
        int x = (t >= o) ? s[t - o] : 0;
        __syncthreads();
        s[t] += x;
        __syncthreads();
    }
    off[(size_t)t * ng2 + b2] = s[t] - v;               // block-major (scattered)
    if (t == 255) binTot[b2] = s[255];
}

// 2 blocks x 1024: block 0 scans S bin totals, block 1 scans D bin totals.
__global__ __launch_bounds__(1024) void k_binbase(const int* __restrict__ binTot,
                                                  int* __restrict__ baseS, int* __restrict__ baseD,
                                                  int* __restrict__ rowptr,
                                                  int E, int ng, int N) {
    __shared__ int buf[1024];
    int t = threadIdx.x;
    int isD = blockIdx.x;
    int sum = (t < ng) ? binTot[isD * ng + t] : 0;
    buf[t] = sum;
    __syncthreads();
    for (int o = 1; o < 1024; o <<= 1) {
        int v = (t >= o) ? buf[t - o] : 0;
        __syncthreads();
        buf[t] += v;
        __syncthreads();
    }
    int base = buf[t] - sum;                            // exclusive
    int* B = isD ? baseD : baseS;
    if (t < ng) B[t] = base;
    if (t == 0) { B[ng] = E; if (!isD) rowptr[N] = E; }
}

// single-pass tile-staged scatter: both keyings staged per 2048-edge tile.
// Per tile: rank (LDS atomics) -> dual 256-bin scan -> sort into LDS ->
// coalesced flush of both staging buffers.
__global__ __launch_bounds__(1024) void k_scatter(const int* __restrict__ src,
                                                  const int* __restrict__ dst,
                                                  const float* __restrict__ w,
                                                  const int* __restrict__ off,
                                                  const int* __restrict__ baseS,
                                                  const int* __restrict__ baseD,
                                                  int2* __restrict__ tmpS, int2* __restrict__ tmpD,
                                                  int E, int chunk, int ng) {
    __shared__ int2 stageS[TILE], stageD[TILE];   // 16 KB each
    __shared__ int cntS[SBINS], cntD[SBINS];      // tile-local offsets
    __shared__ int gcS[SBINS], gcD[SBINS];        // running global cursors
    int t = threadIdx.x, b = blockIdx.x;
    int beg = b * chunk, end = min(E, beg + chunk);
    int ng2 = 2 * ng;
    if (t < ng) {
        gcS[t] = off[(size_t)b * ng2 + t] + baseS[t];
        gcD[t] = off[(size_t)b * ng2 + ng + t] + baseD[t];
    }
    __syncthreads();

    for (int tb = beg; tb < end; tb += TILE) {
        int tcount = min(TILE, end - tb);
        if (t < SBINS) { cntS[t] = 0; cntD[t] = 0; }
        __syncthreads();

        // load + rank both keyings (2 items per thread)
        int gS_[2], rS_[2], gD_[2], rD_[2];
        int2 pS_[2], pD_[2];
        #pragma unroll
        for (int u = 0; u < 2; ++u) {
            int li = u * 1024 + t;
            gS_[u] = -1;
            if (li < tcount) {
                int e = tb + li;
                int s = src[e], d = dst[e];
                int wb = __float_as_int(w[e]);
                int gs = s >> GSH, gd = d >> GSH;
                pS_[u] = make_int2(s, wb);
                pD_[u] = make_int2(s | ((d & (GW - 1)) << 16) | (gd << 24), wb);
                gS_[u] = gs; gD_[u] = gd;
                rS_[u] = atomicAdd(&cntS[gs], 1);
                rD_[u] = atomicAdd(&cntD[gd], 1);
            }
        }
        __syncthreads();

        // dual exclusive scan: threads 0-255 scan cntS, 256-511 scan cntD
        int lt = t & 255;
        bool isS = (t < 256), isD2 = (t >= 256 && t < 512);
        int origS = isS ? cntS[lt] : 0;
        int origD = isD2 ? cntD[lt] : 0;
        for (int o = 1; o < SBINS; o <<= 1) {
            int vS = (isS && lt >= o) ? cntS[lt - o] : 0;
            int vD = (isD2 && lt >= o) ? cntD[lt - o] : 0;
            __syncthreads();
            if (isS && lt >= o) cntS[lt] += vS;
            if (isD2 && lt >= o) cntD[lt] += vD;
            __syncthreads();
        }
        if (isS) cntS[lt] -= origS;                 // exclusive
        if (isD2) cntD[lt] -= origD;
        __syncthreads();

        // place into staging (tiles now sorted by group)
        #pragma unroll
        for (int u = 0; u < 2; ++u) {
            if (gS_[u] >= 0) {
                stageS[cntS[gS_[u]] + rS_[u]] = pS_[u];
                stageD[cntD[gD_[u]] + rD_[u]] = pD_[u];
            }
        }
        __syncthreads();

        // coalesced flush: consecutive i in a group -> consecutive addrs
        for (int i = t; i < tcount; i += 1024) {
            int2 p = stageS[i];
            int g = p.x >> GSH;                      // s>>8 (< 256)
            tmpS[gcS[g] + (i - cntS[g])] = p;
            int2 q = stageD[i];
            int g2 = (q.x >> 24) & 255;
            tmpD[gcD[g2] + (i - cntD[g2])] = q;
        }
        __syncthreads();

        if (isS) gcS[lt] += origS;
        if (isD2) gcD[lt] += origD;
        __syncthreads();
    }
}

// per src-group: LDS float histogram over low 8 bits -> dinv (no global atomics)
__global__ __launch_bounds__(1024) void k_degsum(const int2* __restrict__ tmpS,
                                                 const int* __restrict__ baseS,
                                                 float* __restrict__ dinv, int N) {
    __shared__ float h[GW];
    int g = blockIdx.x, t = threadIdx.x;
    if (t < GW) h[t] = 0.0f;
    __syncthreads();
    int beg = baseS[g], end = baseS[g + 1];
    for (int i = beg + t; i < end; i += 1024) {
        int2 p = tmpS[i];
        atomicAdd(&h[p.x & (GW - 1)], __int_as_float(p.y));
    }
    __syncthreads();
    if (t < GW) {
        int n = (g << GSH) + t;
        if (n < N) { float s = h[t]; dinv[n] = (s > 0.0f) ? rsqrtf(s) : 0.0f; }
    }
}

// per dst-group: low-bits count + scan -> rowptr; then bin edges to exact dst,
// computing nw now that dinv exists. Within-dst order is arbitrary (sum).
__global__ __launch_bounds__(1024) void k_scatter2(const int2* __restrict__ tmpD,
                                                   const int* __restrict__ baseD,
                                                   const float* __restrict__ dinv,
                                                   int* __restrict__ rowptr,
                                                   int2* __restrict__ epair, int N) {
    __shared__ int h[GW], cur[GW];
    int g = blockIdx.x, t = threadIdx.x;
    if (t < GW) h[t] = 0;
    __syncthreads();
    int beg = baseD[g], end = baseD[g + 1];
    for (int i = beg + t; i < end; i += 1024) atomicAdd(&h[(tmpD[i].x >> 16) & (GW - 1)], 1);
    __syncthreads();
    int v = (t < GW) ? h[t] : 0;
    for (int o = 1; o < GW; o <<= 1) {
        int x = (t < GW && t >= o) ? h[t - o] : 0;
        __syncthreads();
        if (t < GW && t >= o) h[t] += x;
        __syncthreads();
    }
    if (t < GW) {
        int excl = h[t] - v;
        int n = (g << GSH) + t;
        if (n < N) rowptr[n] = beg + excl;
        cur[t] = beg + excl;
    }
    __syncthreads();
    for (int i = beg + t; i < end; i += 1024) {
        int2 p = tmpD[i];
        int low = (p.x >> 16) & (GW - 1);
        int s = p.x & 0xFFFF;
        int pos = atomicAdd(&cur[low], 1);
        float nw = -dinv[s] * __int_as_float(p.y) * dinv[(g << GSH) + low];
        epair[pos] = make_int2(s, __float_as_int(nw));
    }
}

// per dst node (32 lanes = 32 feats): accumulate LX (and LH if h0 nonzero)
__global__ __launch_bounds__(256) void k_gather(const int* __restrict__ rowptr,
                                                const int2* __restrict__ epair,
                                                const float* __restrict__ X,
                                                const float* __restrict__ H0,
                                                const int* __restrict__ hflag,
                                                float* __restrict__ LX, float* __restrict__ LH,
                                                int N) {
    int tid = blockIdx.x * 256 + threadIdx.x;
    int n = tid >> 5;
    int f = tid & 31;
    if (n >= N) return;
    int beg = rowptr[n], end = rowptr[n + 1];
    float acc = 0.0f, accH = 0.0f;
    int fl = *hflag;
    if (fl & 1) {
        #pragma unroll 4
        for (int i = beg; i < end; ++i) {
            int2 p = epair[i];
            float w = __int_as_float(p.y);
            acc  += w * X[(p.x << 5) + f];
            accH += w * H0[(p.x << 5) + f];
        }
    } else {
        #pragma unroll 4
        for (int i = beg; i < end; ++i) {
            int2 p = epair[i];
            acc += __int_as_float(p.y) * X[(p.x << 5) + f];
        }
    }
    LX[(n << 5) + f] = acc;
    if (fl & 1) LH[(n << 5) + f] = accH;   // LH is logically 0 otherwise; never read then
}

// Per (node-group g of NPT nodes, out-feature j): fused LSTM cell (no head).
// Fast path (h0==0 && c0==0, detected at runtime): F-gate dead (C = I*T),
// h/lh terms are exact zero-adds -> 3 gates x 2 input types. Bit-identical.
__global__ __launch_bounds__(256) void k_gates(
    const float* __restrict__ X, const float* __restrict__ LX,
    const float* __restrict__ H0, const float* __restrict__ LH,
    const float* __restrict__ C0,
    const float* __restrict__ Wx, const float* __restrict__ bx,
    const float* __restrict__ Wh, const float* __restrict__ bh,
    const float* __restrict__ wc, const float* __restrict__ b,
    const int* __restrict__ flag,
    float* __restrict__ outH, float* __restrict__ outC, int N) {
    int tid = blockIdx.x * 256 + threadIdx.x;
    int g = tid >> 5;           // node group
    int j = tid & 31;           // output feature
    int n0 = g * NPT;
    if (n0 >= N) return;
    int cnt = min(NPT, N - n0);
    int f2 = *flag;

    if (f2 == 0) {
        // ---- fast path: h0 == 0 and c0 == 0 ----
        float xk[NPT], lxk[NPT];
        #pragma unroll
        for (int i = 0; i < NPT; ++i) { xk[i] = 0.0f; lxk[i] = 0.0f; }
        for (int i = 0; i < cnt; ++i) {
            int base = (n0 + i) << 5;
            xk[i]  = X[base + j];
            lxk[i] = LX[base + j];
        }
        float p0[NPT], p2[NPT], p3[NPT];
        float b0 = bx[0 * HID + j] + bh[0 * HID + j] + b[0 * HID + j];
        float b2 = bx[2 * HID + j] + bh[2 * HID + j] + b[2 * HID + j];
        float b3 = bx[3 * HID + j] + bh[3 * HID + j] + b[3 * HID + j];
        #pragma unroll
        for (int i = 0; i < NPT; ++i) { p0[i] = b0; p2[i] = b2; p3[i] = b3; }

        #pragma unroll 4
        for (int k = 0; k < HID; ++k) {
            int row = k * HID + j;
            float w00 = Wx[row],            w01 = Wx[1024 + row];
            float w20 = Wx[2 * 2048 + row], w21 = Wx[2 * 2048 + 1024 + row];
            float w30 = Wx[3 * 2048 + row], w31 = Wx[3 * 2048 + 1024 + row];
            #pragma unroll
            for (int i = 0; i < NPT; ++i) {
                float xv  = __shfl(xk[i],  k, 32);
                float lxv = __shfl(lxk[i], k, 32);
                p0[i] += xv * w00 + lxv * w01;
                p2[i] += xv * w20 + lxv * w21;
                p3[i] += xv * w30 + lxv * w31;
            }
        }

        float wc2 = wc[2 * HID + j];
        for (int i = 0; i < cnt; ++i) {
            int base = (n0 + i) << 5;
            float I = sigmoidf_(p0[i]);
            float T = tanhf(p2[i]);
            float C = I * T;
            float O = sigmoidf_(p3[i] + wc2 * C);
            outH[base + j] = O * tanhf(C);
            outC[base + j] = C;
        }
        return;
    }

    // ---- general path ----
    float xk[NPT], lxk[NPT], hk[NPT], lhk[NPT];
    #pragma unroll
    for (int i = 0; i < NPT; ++i) { xk[i] = 0.0f; lxk[i] = 0.0f; hk[i] = 0.0f; lhk[i] = 0.0f; }
    for (int i = 0; i < cnt; ++i) {
        int base = (n0 + i) << 5;
        xk[i]  = X[base + j];
        lxk[i] = LX[base + j];
        hk[i]  = H0[base + j];
        lhk[i] = (f2 & 1) ? LH[base + j] : 0.0f;   // LH only valid if h0 nonzero
    }

    float pre[4][NPT];
    #pragma unroll
    for (int gt = 0; gt < 4; ++gt) {
        float bb = bx[gt * HID + j] + bh[gt * HID + j] + b[gt * HID + j];
        #pragma unroll
        for (int i = 0; i < NPT; ++i) pre[gt][i] = bb;
    }

    #pragma unroll 2
    for (int k = 0; k < HID; ++k) {
        float w0[4], w1[4], w2[4], w3[4];
        int row = k * HID + j;
        #pragma unroll
        for (int gt = 0; gt < 4; ++gt) {
            w0[gt] = Wx[gt * 2048 + row];
            w1[gt] = Wx[gt * 2048 + 1024 + row];
            w2[gt] = Wh[gt * 2048 + row];
            w3[gt] = Wh[gt * 2048 + 1024 + row];
        }
        #pragma unroll
        for (int i = 0; i < NPT; ++i) {
            float xv  = __shfl(xk[i],  k, 32);
            float lxv = __shfl(lxk[i], k, 32);
            float hv  = __shfl(hk[i],  k, 32);
            float lhv = __shfl(lhk[i], k, 32);
            #pragma unroll
            for (int gt = 0; gt < 4; ++gt)
                pre[gt][i] += xv * w0[gt] + lxv * w1[gt] + hv * w2[gt] + lhv * w3[gt];
        }
    }

    float wc0 = wc[0 * HID + j], wc1 = wc[1 * HID + j], wc2 = wc[2 * HID + j];
    for (int i = 0; i < cnt; ++i) {
        int base = (n0 + i) << 5;
        float c0v = C0[base + j];
        float I  = sigmoidf_(pre[0][i] + wc0 * c0v);
        float Fg = sigmoidf_(pre[1][i] + wc1 * c0v);
        float T  = tanhf(pre[2][i]);
        float C  = Fg * c0v + I * T;
        float O  = sigmoidf_(pre[3][i] + wc2 * C);
        float H  = O * tanhf(C);
        outH[base + j] = H;
        outC[base + j] = C;
    }
}

// h[n,t] = b_lin[t] + sum_k relu(H[n,k]) * W_lin[k,t]
__global__ void k_head(const float* __restrict__ H, const float* __restrict__ Wl,
                       const float* __restrict__ bl, float* __restrict__ hout, int N) {
    int tid = blockIdx.x * 256 + threadIdx.x;
    int n = tid / HOR;
    int t = tid - n * HOR;
    if (n >= N) return;
    float acc = bl[t];
    #pragma unroll
    for (int k = 0; k < HID; ++k) {
        float v = H[(n << 5) + k];
        acc += fmaxf(v, 0.0f) * Wl[k * HOR + t];
    }
    hout[n * HOR + t] = acc;
}

extern "C" void kernel_launch(void* const* d_in, const int* in_sizes, int n_in,
                              void* d_out, int out_size, void* d_ws, size_t ws_size,
                              hipStream_t stream) {
    const float* x  = (const float*)d_in[0];
    const int*   ei = (const int*)d_in[1];
    const float* ew = (const float*)d_in[2];
    const float* Wx = (const float*)d_in[3];
    const float* bx = (const float*)d_in[4];
    const float* Wh = (const float*)d_in[5];
    const float* bh = (const float*)d_in[6];
    const float* wc = (const float*)d_in[7];
    const float* b  = (const float*)d_in[8];
    const float* Wl = (const float*)d_in[9];
    const float* bl = (const float*)d_in[10];
    const float* h0 = (const float*)d_in[11];
    const float* c0 = (const float*)d_in[12];

    int N = in_sizes[0] / HID;      // x is (N,1,32)
    int E = in_sizes[2];            // edge_weight is (E,)
    const int* src = ei;
    const int* dst = ei + E;

    int ng = (N + GW - 1) >> GSH;   // 196 groups (requires N <= 65536)
    int ng2 = 2 * ng;
    int chunk = (E + NB - 1) / NB;  // edges per hist/scatter block

    // workspace (4-byte units):
    // [tmpD 2E] [tmpS 2E (aliased by epair)] [LX N*32] [LH N*32] [rowptr N+1]
    // [hist ng2*NB] [off ng2*NB] [binTot 2048] [baseS ng+1] [baseD ng+1]
    // [dinv N] [flag 1]
    // tmpS is dead after k_degsum, so k_scatter2 may overwrite it with epair.
    int* wsi = (int*)d_ws;
    int2*  tmpD   = (int2*)wsi;
    int2*  tmpS   = (int2*)(wsi + 2 * (size_t)E);
    int2*  epair  = tmpS;                                // alias (see above)
    float* LX     = (float*)(wsi + 4 * (size_t)E);
    float* LH     = LX + (size_t)N * HID;
    int*   rowptr = (int*)(LH + (size_t)N * HID);
    int*   hist   = rowptr + (N + 1);
    int*   off    = hist + (size_t)ng2 * NB;
    int*   binTot = off + (size_t)ng2 * NB;
    int*   baseS  = binTot + 2048;
    int*   baseD  = baseS + (ng + 1);
    float* dinv   = (float*)(baseD + (ng + 1));
    int*   flag   = (int*)(dinv + N);

    float* hOut = (float*)d_out;            // (N,12)
    float* HOut = hOut + (size_t)N * HOR;   // (N,32)
    float* COut = HOut + (size_t)N * HID;   // (N,32)

    hipMemsetAsync(flag, 0, sizeof(int), stream);

    k_hist<<<NB, 1024, 0, stream>>>(src, dst, hist, h0, c0, flag, E, chunk, ng, (N * HID) >> 2);
    k_binscan<<<ng2, 256, 0, stream>>>(hist, off, binTot, ng2);
    k_binbase<<<2, 1024, 0, stream>>>(binTot, baseS, baseD, rowptr, E, ng, N);
    k_scatter<<<NB, 1024, 0, stream>>>(src, dst, ew, off, baseS, baseD, tmpS, tmpD, E, chunk, ng);
    k_degsum<<<ng, 1024, 0, stream>>>(tmpS, baseS, dinv, N);
    k_scatter2<<<ng, 1024, 0, stream>>>(tmpD, baseD, dinv, rowptr, epair, N);

    k_gather<<<(N * HID + 255) / 256, 256, 0, stream>>>(rowptr, epair, x, h0, flag, LX, LH, N);

    int gThreads = ((N + NPT - 1) / NPT) * 32;
    k_gates<<<(gThreads + 255) / 256, 256, 0, stream>>>(x, LX, h0, LH, c0,
                                                        Wx, bx, Wh, bh, wc, b, flag,
                                                        HOut, COut, N);

    k_head<<<(N * HOR + 255) / 256, 256, 0, stream>>>(HOut, Wl, bl, hOut, N);
}